// Round 13
// baseline (141.573 us; speedup 1.0000x reference)
//
#include <hip/hip_runtime.h>
#include <hip/hip_bf16.h>

// 2-layer GCN on MI355X, round 12 (resubmit: r12 bench was lost to a GPU
// acquisition timeout -- identical kernel, same prediction).
// r11 accounting: kernels ~65us, inter-dispatch overhead ~55us (11-12us each)
// -> cut dispatches 5->4 and shrink the middle kernels.
//  k_bin    : deterministic per-(bin,blk) segments + cnts table (NO global
//             atomics, NO memset needed), + w2t build.
//  k_bucket : single walk -- placement cursor IS the histogram; deg/d5/xd.
//  k_agg2   : bin-wise agg via LDS f32 atomics over the same segments.
//  k_l2     : r10/r11 staged gather + MFMA epilogue, verbatim (proven).

constexpr int NN = 50000;
constexpr int NE = 800000;
constexpr int CAP = 64;        // slots per node; in-deg ~ Poisson(16)
constexpr int NBIN = 391;      // 128-wide dst bins (bin = d >> 7)
constexpr int NBLKB = 391;     // k_bin blocks (2048 edges each)
constexpr int SEGCAP = 32;     // per-(bin,blk) capacity; lambda 5.2 -> P(ovf) ~ 1e-8
constexpr int CSTR = 392;      // cnts row stride (padded)
constexpr int NB_TILE = 3128;  // ceil(50000/16)

typedef __attribute__((ext_vector_type(8))) short bf16x8;
typedef __attribute__((ext_vector_type(4))) float f32x4;

#define ALIGN_UP(x, a) (((x) + (a) - 1) / (a) * (a))

struct Args {
    const float4* x;
    const int4* src4;
    const int4* dst4;
    const float* W1;
    const float* b1;
    const float* W2;
    const float* b2;
    int* cnts;               // [NBIN][CSTR] per-(bin,blk) segment counts
    unsigned int* binned;    // [NBIN][NBLKB][SEGCAP] packed (dlocal<<16)|src
    int* deg;                // [NN] (clamped to CAP)
    unsigned short* slots;   // [NN*CAP] src ids
    float4* xd;              // x[n]*dinv[n]
    float4* aggS;            // (A_hat x)[n]*dinv[n]
    float* d5;               // dinv[n]
    __hip_bfloat16* w2t;     // w2t[c][k] = bf16(W2[k][c])
    float* out;
};

// Bin 2048 edges/block into per-(bin,blk) segments; LDS cursors only.
// cnts[bin][blk] = min(count,SEGCAP) via plain stores. Block 0 builds w2t.
__global__ __launch_bounds__(512) void k_bin(Args a) {
    __shared__ int lcur[NBIN];
    int t = threadIdx.x, blk = blockIdx.x;
    for (int i = t; i < NBIN; i += 512) lcur[i] = 0;
    __syncthreads();
    int idx4 = blk * 512 + t;
    if (idx4 < NE / 4) {
        int4 s = a.src4[idx4];
        int4 d = a.dst4[idx4];
#pragma unroll
        for (int c = 0; c < 4; ++c) {
            int dv = (c == 0) ? d.x : (c == 1) ? d.y : (c == 2) ? d.z : d.w;
            int sv = (c == 0) ? s.x : (c == 1) ? s.y : (c == 2) ? s.z : s.w;
            int b = dv >> 7;
            int pos = atomicAdd(&lcur[b], 1);
            if (pos < SEGCAP)
                a.binned[((size_t)b * NBLKB + blk) * SEGCAP + pos] =
                    ((unsigned)(dv & 127) << 16) | (unsigned)sv;
        }
    }
    __syncthreads();
    for (int i = t; i < NBIN; i += 512)
        a.cnts[i * CSTR + blk] = lcur[i] < SEGCAP ? lcur[i] : SEGCAP;

    if (blk == 0) {
        for (int idx = t; idx < 4096; idx += 512) {
            int c = idx >> 6, k = idx & 63;
            a.w2t[idx] = __float2bfloat16(a.W2[k * 64 + c]);
        }
    }
}

// One block per bin (128 nodes). Single walk: placement cursor doubles as
// the degree histogram. Then deg/d5/xd written coalesced.
__global__ __launch_bounds__(512) void k_bucket(Args a) {
    __shared__ int cnt_s[NBIN];
    __shared__ int cur[128];
    int t = threadIdx.x, b = blockIdx.x;
    int wv = t >> 6, lane = t & 63;
    if (t < 128) cur[t] = 0;
    for (int i = t; i < NBIN; i += 512) cnt_s[i] = a.cnts[b * CSTR + i];
    __syncthreads();
    // 2 segments per wave-iteration (lane>>5 picks one; cnt <= 32).
    for (int it = wv * 2 + (lane >> 5); it < NBLKB; it += 16) {
        int c = cnt_s[it];
        int l = lane & 31;
        if (l < c) {
            unsigned e = a.binned[((size_t)b * NBLKB + it) * SEGCAP + l];
            int dl = e >> 16;
            int pos = atomicAdd(&cur[dl], 1);
            if (pos < CAP)
                a.slots[((size_t)(b * 128 + dl)) * CAP + pos] = (unsigned short)(e & 0xFFFF);
        }
    }
    __syncthreads();
    if (t < 128) {
        int d = b * 128 + t;
        if (d < NN) {
            int raw = cur[t];
            float di = rsqrtf((float)(raw + 1));
            a.deg[d] = raw < CAP ? raw : CAP;
            a.d5[d] = di;
            float4 xs = a.x[d];
            a.xd[d] = make_float4(xs.x * di, xs.y * di, xs.z * di, xs.w * di);
        }
    }
}

// One block per bin: aggS[d] = x[d]*di^3 + di^2 * sum_s xd[s], accumulated
// in LDS f32 atomics over the bin's edge segments (xd reads are L2-resident).
__global__ __launch_bounds__(512) void k_agg2(Args a) {
    __shared__ int cnt_s[NBIN];
    __shared__ float acc[128][4];
    int t = threadIdx.x, b = blockIdx.x;
    int wv = t >> 6, lane = t & 63;
    reinterpret_cast<float*>(acc)[t] = 0.f;  // 512 floats exactly
    for (int i = t; i < NBIN; i += 512) cnt_s[i] = a.cnts[b * CSTR + i];
    __syncthreads();
    for (int it = wv * 2 + (lane >> 5); it < NBLKB; it += 16) {
        int c = cnt_s[it];
        int l = lane & 31;
        if (l < c) {
            unsigned e = a.binned[((size_t)b * NBLKB + it) * SEGCAP + l];
            int dl = e >> 16;
            float4 v = a.xd[e & 0xFFFF];
            atomicAdd(&acc[dl][0], v.x);
            atomicAdd(&acc[dl][1], v.y);
            atomicAdd(&acc[dl][2], v.z);
            atomicAdd(&acc[dl][3], v.w);
        }
    }
    __syncthreads();
    if (t < 128) {
        int d = b * 128 + t;
        if (d < NN) {
            float di = a.d5[d];
            float di2 = di * di, di3 = di2 * di;
            float4 xs = a.x[d];
            a.aggS[d] = make_float4(fmaf(acc[t][0], di2, xs.x * di3),
                                    fmaf(acc[t][1], di2, xs.y * di3),
                                    fmaf(acc[t][2], di2, xs.z * di3),
                                    fmaf(acc[t][3], di2, xs.w * di3));
        }
    }
}

// Layer 2 fused (r10/r11 structure, verbatim): 512-thr block = 8 waves per
// 16-node tile. Stage: lane-parallel gather slot->aggS,d5 into LDS. Compute:
// per-channel sweep; m = dot4(stA,W1col) + b1c*stQ; acc += relu(m); self-loop
// = edge s=d; acc *= d5[d]. Then bf16 tile -> 2x mfma 16x16x32 (waves 0-3).
__global__ __launch_bounds__(512) void k_l2(Args a) {
    __shared__ float4 stA[16][CAP];          // 16 KB
    __shared__ float4 stQ4[16][CAP / 4];     // 4 KB
    __shared__ __hip_bfloat16 tile[16][72];  // 2.3 KB
    int tid = threadIdx.x;
    int wv = tid >> 6, lane = tid & 63;
    int base = blockIdx.x * 16;

    int degR[2];
#pragma unroll
    for (int rr = 0; rr < 2; ++rr) {
        int row = wv * 2 + rr;
        int node = base + row;
        degR[rr] = 0;
        if (node < NN) {
            int deg = a.deg[node];
            degR[rr] = deg;
            const unsigned short* sl = a.slots + (size_t)node * CAP;
            if (lane < deg) {
                int s = sl[lane];
                stA[row][lane] = a.aggS[s];
                reinterpret_cast<float*>(&stQ4[row][0])[lane] = a.d5[s];
            }
        }
    }

    float w0 = a.W1[lane], w1 = a.W1[64 + lane];
    float w2 = a.W1[128 + lane], w3 = a.W1[192 + lane];
    float b1c = a.b1[lane];
#pragma unroll
    for (int rr = 0; rr < 2; ++rr) {
        int row = wv * 2 + rr;
        int node = base + row;
        float acc = 0.f;
        if (node < NN) {
            int deg = degR[rr];
            float4 as = a.aggS[node];
            float dn = a.d5[node];
            float ms = fmaf(as.x, w0, fmaf(as.y, w1,
                        fmaf(as.z, w2, fmaf(as.w, w3, b1c * dn))));
            acc = fmaxf(ms, 0.f);  // self-loop message
            int j = 0;
            for (; j + 3 < deg; j += 4) {
                float4 q4 = stQ4[row][j >> 2];
                float4 e0 = stA[row][j],     e1 = stA[row][j + 1];
                float4 e2 = stA[row][j + 2], e3 = stA[row][j + 3];
                float m0 = fmaf(e0.x, w0, fmaf(e0.y, w1, fmaf(e0.z, w2, fmaf(e0.w, w3, b1c * q4.x))));
                float m1 = fmaf(e1.x, w0, fmaf(e1.y, w1, fmaf(e1.z, w2, fmaf(e1.w, w3, b1c * q4.y))));
                float m2 = fmaf(e2.x, w0, fmaf(e2.y, w1, fmaf(e2.z, w2, fmaf(e2.w, w3, b1c * q4.z))));
                float m3 = fmaf(e3.x, w0, fmaf(e3.y, w1, fmaf(e3.z, w2, fmaf(e3.w, w3, b1c * q4.w))));
                acc += fmaxf(m0, 0.f);
                acc += fmaxf(m1, 0.f);
                acc += fmaxf(m2, 0.f);
                acc += fmaxf(m3, 0.f);
            }
            for (; j < deg; ++j) {
                float4 e0 = stA[row][j];
                float q = reinterpret_cast<const float*>(&stQ4[row][0])[j];
                float m0 = fmaf(e0.x, w0, fmaf(e0.y, w1,
                            fmaf(e0.z, w2, fmaf(e0.w, w3, b1c * q))));
                acc += fmaxf(m0, 0.f);
            }
            acc *= dn;
        }
        tile[row][lane] = __float2bfloat16(acc);
    }
    __syncthreads();

    if (wv < 4) {
        int g = lane >> 4, c16 = lane & 15;
        int col = wv * 16 + c16;
        bf16x8 a0 = *reinterpret_cast<const bf16x8*>(&tile[c16][g * 8]);
        bf16x8 a1 = *reinterpret_cast<const bf16x8*>(&tile[c16][32 + g * 8]);
        bf16x8 bb0 = *reinterpret_cast<const bf16x8*>(a.w2t + col * 64 + g * 8);
        bf16x8 bb1 = *reinterpret_cast<const bf16x8*>(a.w2t + col * 64 + 32 + g * 8);
        f32x4 acc4 = {0.f, 0.f, 0.f, 0.f};
        acc4 = __builtin_amdgcn_mfma_f32_16x16x32_bf16(a0, bb0, acc4, 0, 0, 0);
        acc4 = __builtin_amdgcn_mfma_f32_16x16x32_bf16(a1, bb1, acc4, 0, 0, 0);
        float b2v = a.b2[col];
#pragma unroll
        for (int rg = 0; rg < 4; ++rg) {
            int node = base + g * 4 + rg;
            if (node < NN) a.out[node * 64 + col] = fmaxf(acc4[rg] + b2v, 0.f);
        }
    }
}

extern "C" void kernel_launch(void* const* d_in, const int* in_sizes, int n_in,
                              void* d_out, int out_size, void* d_ws, size_t ws_size,
                              hipStream_t stream) {
    const float* x  = (const float*)d_in[0];
    const int*   ei = (const int*)d_in[1];  // [2, NE]: src row then dst row
    const float* W1 = (const float*)d_in[2];
    const float* b1 = (const float*)d_in[3];
    const float* W2 = (const float*)d_in[4];
    const float* b2 = (const float*)d_in[5];

    char* w = (char*)d_ws;
    auto take = [&](size_t bytes) { char* p = w; w += ALIGN_UP(bytes, 256); return p; };
    int*            cnts   = (int*)           take((size_t)NBIN * CSTR * 4);          // 613 KB
    unsigned int*   binned = (unsigned int*)  take((size_t)NBIN * NBLKB * SEGCAP * 4); // 19.6 MB
    int*            deg    = (int*)           take((size_t)NN * 4);
    unsigned short* slots  = (unsigned short*)take((size_t)NN * CAP * 2);             // 6.4 MB
    float*          xd     = (float*)         take((size_t)NN * 16);
    float*          aggS   = (float*)         take((size_t)NN * 16);
    float*          d5     = (float*)         take((size_t)NN * 4);
    __hip_bfloat16* w2t    = (__hip_bfloat16*)take(4096 * 2);

    Args args;
    args.x = (const float4*)x;
    args.src4 = (const int4*)ei;
    args.dst4 = (const int4*)(ei + NE);
    args.W1 = W1; args.b1 = b1; args.W2 = W2; args.b2 = b2;
    args.cnts = cnts; args.binned = binned; args.deg = deg;
    args.slots = slots; args.xd = (float4*)xd;
    args.aggS = (float4*)aggS; args.d5 = d5; args.w2t = w2t;
    args.out = (float*)d_out;

    k_bin<<<NBLKB, 512, 0, stream>>>(args);     // 391 blocks
    k_bucket<<<NBIN, 512, 0, stream>>>(args);   // 391 blocks
    k_agg2<<<NBIN, 512, 0, stream>>>(args);     // 391 blocks
    k_l2<<<NB_TILE, 512, 0, stream>>>(args);    // 3128 blocks
}

// Round 14
// 141.272 us; speedup vs baseline: 1.0021x; 1.0021x over previous
//
#include <hip/hip_runtime.h>
#include <hip/hip_bf16.h>

// 2-layer GCN on MI355X, round 14.
// r13 regression diagnosis: binned[(bin*NBLKB+blk)] made every k_bin block
// scatter partial-line stores across 19.6MB (391 lines at 50KB stride) --
// write-allocate RMW, the same costly pattern as global atomics. Fix (ONE
// change from r13): transpose to binned[(blk*NBIN+bin)] so each block WRITES
// a private contiguous 50KB region; k_bucket/k_agg2 absorb scattered 128B
// READS instead (sector fetches, LLC-resident, TLP-covered).
//  k_bin    : segment build, no global atomics, no memset; + w2t.
//  k_bucket : single walk; placement cursor doubles as histogram; deg/d5/xd.
//  k_agg2   : bin-wise agg via LDS f32 atomics over the same segments.
//  k_l2     : r10/r11 staged gather + MFMA epilogue, verbatim (proven).

constexpr int NN = 50000;
constexpr int NE = 800000;
constexpr int CAP = 64;        // slots per node; in-deg ~ Poisson(16)
constexpr int NBIN = 391;      // 128-wide dst bins (bin = d >> 7)
constexpr int NBLKB = 391;     // k_bin blocks (2048 edges each)
constexpr int SEGCAP = 32;     // per-(blk,bin) capacity; lambda 5.2 -> P(ovf) ~ 1e-8
constexpr int CSTR = 392;      // cnts row stride (padded)
constexpr int NB_TILE = 3128;  // ceil(50000/16)

typedef __attribute__((ext_vector_type(8))) short bf16x8;
typedef __attribute__((ext_vector_type(4))) float f32x4;

#define ALIGN_UP(x, a) (((x) + (a) - 1) / (a) * (a))

struct Args {
    const float4* x;
    const int4* src4;
    const int4* dst4;
    const float* W1;
    const float* b1;
    const float* W2;
    const float* b2;
    int* cnts;               // [NBIN][CSTR] per-(bin,blk) segment counts
    unsigned int* binned;    // [NBLKB][NBIN][SEGCAP] packed (dlocal<<16)|src
    int* deg;                // [NN] (clamped to CAP)
    unsigned short* slots;   // [NN*CAP] src ids
    float4* xd;              // x[n]*dinv[n]
    float4* aggS;            // (A_hat x)[n]*dinv[n]
    float* d5;               // dinv[n]
    __hip_bfloat16* w2t;     // w2t[c][k] = bf16(W2[k][c])
    float* out;
};

// Bin 2048 edges/block into this block's PRIVATE contiguous segment region
// (blk*NBIN*SEGCAP .. +50KB); LDS cursors only. cnts[bin][blk] via plain
// stores. Block 0 also builds w2t.
__global__ __launch_bounds__(512) void k_bin(Args a) {
    __shared__ int lcur[NBIN];
    int t = threadIdx.x, blk = blockIdx.x;
    for (int i = t; i < NBIN; i += 512) lcur[i] = 0;
    __syncthreads();
    int idx4 = blk * 512 + t;
    if (idx4 < NE / 4) {
        int4 s = a.src4[idx4];
        int4 d = a.dst4[idx4];
#pragma unroll
        for (int c = 0; c < 4; ++c) {
            int dv = (c == 0) ? d.x : (c == 1) ? d.y : (c == 2) ? d.z : d.w;
            int sv = (c == 0) ? s.x : (c == 1) ? s.y : (c == 2) ? s.z : s.w;
            int b = dv >> 7;
            int pos = atomicAdd(&lcur[b], 1);
            if (pos < SEGCAP)
                a.binned[((size_t)blk * NBIN + b) * SEGCAP + pos] =
                    ((unsigned)(dv & 127) << 16) | (unsigned)sv;
        }
    }
    __syncthreads();
    for (int i = t; i < NBIN; i += 512)
        a.cnts[i * CSTR + blk] = lcur[i] < SEGCAP ? lcur[i] : SEGCAP;

    if (blk == 0) {
        for (int idx = t; idx < 4096; idx += 512) {
            int c = idx >> 6, k = idx & 63;
            a.w2t[idx] = __float2bfloat16(a.W2[k * 64 + c]);
        }
    }
}

// One block per bin (128 nodes). Single walk: placement cursor doubles as
// the degree histogram. Then deg/d5/xd written coalesced.
__global__ __launch_bounds__(512) void k_bucket(Args a) {
    __shared__ int cnt_s[NBIN];
    __shared__ int cur[128];
    int t = threadIdx.x, b = blockIdx.x;
    int wv = t >> 6, lane = t & 63;
    if (t < 128) cur[t] = 0;
    for (int i = t; i < NBIN; i += 512) cnt_s[i] = a.cnts[b * CSTR + i];
    __syncthreads();
    // 2 segments per wave-iteration (lane>>5 picks one; cnt <= 32).
    for (int it = wv * 2 + (lane >> 5); it < NBLKB; it += 16) {
        int c = cnt_s[it];
        int l = lane & 31;
        if (l < c) {
            unsigned e = a.binned[((size_t)it * NBIN + b) * SEGCAP + l];
            int dl = e >> 16;
            int pos = atomicAdd(&cur[dl], 1);
            if (pos < CAP)
                a.slots[((size_t)(b * 128 + dl)) * CAP + pos] = (unsigned short)(e & 0xFFFF);
        }
    }
    __syncthreads();
    if (t < 128) {
        int d = b * 128 + t;
        if (d < NN) {
            int raw = cur[t];
            float di = rsqrtf((float)(raw + 1));
            a.deg[d] = raw < CAP ? raw : CAP;
            a.d5[d] = di;
            float4 xs = a.x[d];
            a.xd[d] = make_float4(xs.x * di, xs.y * di, xs.z * di, xs.w * di);
        }
    }
}

// One block per bin: aggS[d] = x[d]*di^3 + di^2 * sum_s xd[s], accumulated
// in LDS f32 atomics over the bin's edge segments (xd reads are L2-resident).
__global__ __launch_bounds__(512) void k_agg2(Args a) {
    __shared__ int cnt_s[NBIN];
    __shared__ float acc[128][4];
    int t = threadIdx.x, b = blockIdx.x;
    int wv = t >> 6, lane = t & 63;
    reinterpret_cast<float*>(acc)[t] = 0.f;  // 512 floats exactly
    for (int i = t; i < NBIN; i += 512) cnt_s[i] = a.cnts[b * CSTR + i];
    __syncthreads();
    for (int it = wv * 2 + (lane >> 5); it < NBLKB; it += 16) {
        int c = cnt_s[it];
        int l = lane & 31;
        if (l < c) {
            unsigned e = a.binned[((size_t)it * NBIN + b) * SEGCAP + l];
            int dl = e >> 16;
            float4 v = a.xd[e & 0xFFFF];
            atomicAdd(&acc[dl][0], v.x);
            atomicAdd(&acc[dl][1], v.y);
            atomicAdd(&acc[dl][2], v.z);
            atomicAdd(&acc[dl][3], v.w);
        }
    }
    __syncthreads();
    if (t < 128) {
        int d = b * 128 + t;
        if (d < NN) {
            float di = a.d5[d];
            float di2 = di * di, di3 = di2 * di;
            float4 xs = a.x[d];
            a.aggS[d] = make_float4(fmaf(acc[t][0], di2, xs.x * di3),
                                    fmaf(acc[t][1], di2, xs.y * di3),
                                    fmaf(acc[t][2], di2, xs.z * di3),
                                    fmaf(acc[t][3], di2, xs.w * di3));
        }
    }
}

// Layer 2 fused (r10/r11 structure, verbatim): 512-thr block = 8 waves per
// 16-node tile. Stage: lane-parallel gather slot->aggS,d5 into LDS. Compute:
// per-channel sweep; m = dot4(stA,W1col) + b1c*stQ; acc += relu(m); self-loop
// = edge s=d; acc *= d5[d]. Then bf16 tile -> 2x mfma 16x16x32 (waves 0-3).
__global__ __launch_bounds__(512) void k_l2(Args a) {
    __shared__ float4 stA[16][CAP];          // 16 KB
    __shared__ float4 stQ4[16][CAP / 4];     // 4 KB
    __shared__ __hip_bfloat16 tile[16][72];  // 2.3 KB
    int tid = threadIdx.x;
    int wv = tid >> 6, lane = tid & 63;
    int base = blockIdx.x * 16;

    int degR[2];
#pragma unroll
    for (int rr = 0; rr < 2; ++rr) {
        int row = wv * 2 + rr;
        int node = base + row;
        degR[rr] = 0;
        if (node < NN) {
            int deg = a.deg[node];
            degR[rr] = deg;
            const unsigned short* sl = a.slots + (size_t)node * CAP;
            if (lane < deg) {
                int s = sl[lane];
                stA[row][lane] = a.aggS[s];
                reinterpret_cast<float*>(&stQ4[row][0])[lane] = a.d5[s];
            }
        }
    }

    float w0 = a.W1[lane], w1 = a.W1[64 + lane];
    float w2 = a.W1[128 + lane], w3 = a.W1[192 + lane];
    float b1c = a.b1[lane];
#pragma unroll
    for (int rr = 0; rr < 2; ++rr) {
        int row = wv * 2 + rr;
        int node = base + row;
        float acc = 0.f;
        if (node < NN) {
            int deg = degR[rr];
            float4 as = a.aggS[node];
            float dn = a.d5[node];
            float ms = fmaf(as.x, w0, fmaf(as.y, w1,
                        fmaf(as.z, w2, fmaf(as.w, w3, b1c * dn))));
            acc = fmaxf(ms, 0.f);  // self-loop message
            int j = 0;
            for (; j + 3 < deg; j += 4) {
                float4 q4 = stQ4[row][j >> 2];
                float4 e0 = stA[row][j],     e1 = stA[row][j + 1];
                float4 e2 = stA[row][j + 2], e3 = stA[row][j + 3];
                float m0 = fmaf(e0.x, w0, fmaf(e0.y, w1, fmaf(e0.z, w2, fmaf(e0.w, w3, b1c * q4.x))));
                float m1 = fmaf(e1.x, w0, fmaf(e1.y, w1, fmaf(e1.z, w2, fmaf(e1.w, w3, b1c * q4.y))));
                float m2 = fmaf(e2.x, w0, fmaf(e2.y, w1, fmaf(e2.z, w2, fmaf(e2.w, w3, b1c * q4.z))));
                float m3 = fmaf(e3.x, w0, fmaf(e3.y, w1, fmaf(e3.z, w2, fmaf(e3.w, w3, b1c * q4.w))));
                acc += fmaxf(m0, 0.f);
                acc += fmaxf(m1, 0.f);
                acc += fmaxf(m2, 0.f);
                acc += fmaxf(m3, 0.f);
            }
            for (; j < deg; ++j) {
                float4 e0 = stA[row][j];
                float q = reinterpret_cast<const float*>(&stQ4[row][0])[j];
                float m0 = fmaf(e0.x, w0, fmaf(e0.y, w1,
                            fmaf(e0.z, w2, fmaf(e0.w, w3, b1c * q))));
                acc += fmaxf(m0, 0.f);
            }
            acc *= dn;
        }
        tile[row][lane] = __float2bfloat16(acc);
    }
    __syncthreads();

    if (wv < 4) {
        int g = lane >> 4, c16 = lane & 15;
        int col = wv * 16 + c16;
        bf16x8 a0 = *reinterpret_cast<const bf16x8*>(&tile[c16][g * 8]);
        bf16x8 a1 = *reinterpret_cast<const bf16x8*>(&tile[c16][32 + g * 8]);
        bf16x8 bb0 = *reinterpret_cast<const bf16x8*>(a.w2t + col * 64 + g * 8);
        bf16x8 bb1 = *reinterpret_cast<const bf16x8*>(a.w2t + col * 64 + 32 + g * 8);
        f32x4 acc4 = {0.f, 0.f, 0.f, 0.f};
        acc4 = __builtin_amdgcn_mfma_f32_16x16x32_bf16(a0, bb0, acc4, 0, 0, 0);
        acc4 = __builtin_amdgcn_mfma_f32_16x16x32_bf16(a1, bb1, acc4, 0, 0, 0);
        float b2v = a.b2[col];
#pragma unroll
        for (int rg = 0; rg < 4; ++rg) {
            int node = base + g * 4 + rg;
            if (node < NN) a.out[node * 64 + col] = fmaxf(acc4[rg] + b2v, 0.f);
        }
    }
}

extern "C" void kernel_launch(void* const* d_in, const int* in_sizes, int n_in,
                              void* d_out, int out_size, void* d_ws, size_t ws_size,
                              hipStream_t stream) {
    const float* x  = (const float*)d_in[0];
    const int*   ei = (const int*)d_in[1];  // [2, NE]: src row then dst row
    const float* W1 = (const float*)d_in[2];
    const float* b1 = (const float*)d_in[3];
    const float* W2 = (const float*)d_in[4];
    const float* b2 = (const float*)d_in[5];

    char* w = (char*)d_ws;
    auto take = [&](size_t bytes) { char* p = w; w += ALIGN_UP(bytes, 256); return p; };
    int*            cnts   = (int*)           take((size_t)NBIN * CSTR * 4);          // 613 KB
    unsigned int*   binned = (unsigned int*)  take((size_t)NBLKB * NBIN * SEGCAP * 4); // 19.6 MB
    int*            deg    = (int*)           take((size_t)NN * 4);
    unsigned short* slots  = (unsigned short*)take((size_t)NN * CAP * 2);             // 6.4 MB
    float*          xd     = (float*)         take((size_t)NN * 16);
    float*          aggS   = (float*)         take((size_t)NN * 16);
    float*          d5     = (float*)         take((size_t)NN * 4);
    __hip_bfloat16* w2t    = (__hip_bfloat16*)take(4096 * 2);

    Args args;
    args.x = (const float4*)x;
    args.src4 = (const int4*)ei;
    args.dst4 = (const int4*)(ei + NE);
    args.W1 = W1; args.b1 = b1; args.W2 = W2; args.b2 = b2;
    args.cnts = cnts; args.binned = binned; args.deg = deg;
    args.slots = slots; args.xd = (float4*)xd;
    args.aggS = (float4*)aggS; args.d5 = d5; args.w2t = w2t;
    args.out = (float*)d_out;

    k_bin<<<NBLKB, 512, 0, stream>>>(args);     // 391 blocks
    k_bucket<<<NBIN, 512, 0, stream>>>(args);   // 391 blocks
    k_agg2<<<NBIN, 512, 0, stream>>>(args);     // 391 blocks
    k_l2<<<NB_TILE, 512, 0, stream>>>(args);    // 3128 blocks
}